// Round 11
// baseline (669.926 us; speedup 1.0000x reference)
//
#include <hip/hip_runtime.h>

static constexpr int NE   = 4096;      // n_embed
static constexpr int ED   = 64;        // embed_dim
static constexpr int NTOK = 65536;     // 4*16*32*32
static constexpr int NCHUNK = 32;      // code-loop split factor
static constexpr int CPC  = NE / NCHUNK;   // codes per chunk = 128

typedef float  f32x2 __attribute__((ext_vector_type(2)));
typedef float  f32x4 __attribute__((ext_vector_type(4)));

// d_out offsets (float elements), outputs concatenated in return order:
// out(4194304), loss(1), perplexity(1), idx(65536), new_embed(262144),
// new_cs(4096), new_ea(262144)
static constexpr long O_OUT  = 0;
static constexpr long O_LOSS = 4194304;
static constexpr long O_PERP = 4194305;
static constexpr long O_IDX  = 4194306;
static constexpr long O_NEMB = 4259842;
static constexpr long O_NCS  = 4521986;
static constexpr long O_NEA  = 4526082;

// ws layout (bytes)
static constexpr size_t W_ACC   = 0;        // double[4]: [0]=loss [1]=n [2]=plog   (zeroed)
static constexpr size_t W_CNT   = 32;       // unsigned[4096] counts                (zeroed)
static constexpr size_t W_CUR   = 16416;    // unsigned[4096] scatter cursors       (zeroed)
static constexpr size_t W_OFF   = 32800;    // unsigned[4096] bucket start offsets
static constexpr size_t W_IDX   = 49184;    // int[65536]
static constexpr size_t W_BKT   = 311328;   // int[65536] token ids bucketed by code
static constexpr size_t W_LOSSP = 573472;   // double[16384] per-block loss partials
static constexpr size_t W_PKD   = 704544;   // uint64[65536] packed (d_bits<<32)|idx
static constexpr size_t W_AUG   = 1228832;  // float[4096*68]: [e row (64), bq, pad(3)]
static constexpr size_t W_ZERO_BYTES = 32800;   // acc + counts + cursors
static constexpr size_t W_PKD_BYTES  = 524288;  // 0xFF-init packed

// ---- augmented codebook: row n = [e_n[0..63], ||e_n||^2, pad] (stride 68) --
__global__ __launch_bounds__(256) void kAug(const float* __restrict__ e,
                                            float* __restrict__ aug) {
    int n = blockIdx.x * 256 + threadIdx.x;        // 0..4095
    const float* er = e + (n << 6);
    float* row = aug + (long)n * 68;
    // bq numerics: identical fmaf 4-partial chain to the 10x-passing kBsq
    float a0 = 0.f, a1 = 0.f, a2 = 0.f, a3 = 0.f;
#pragma unroll
    for (int k = 0; k < ED; k += 4) {
        a0 = fmaf(er[k+0], er[k+0], a0);
        a1 = fmaf(er[k+1], er[k+1], a1);
        a2 = fmaf(er[k+2], er[k+2], a2);
        a3 = fmaf(er[k+3], er[k+3], a3);
    }
#pragma unroll
    for (int k = 0; k < 16; ++k)
        ((f32x4*)row)[k] = ((const f32x4*)er)[k];
    row[64] = (a0 + a1) + (a2 + a3);
}

// 64 named z floats Z0..Z63
#define Z_EACH(F) \
    F(0)  F(1)  F(2)  F(3)  F(4)  F(5)  F(6)  F(7)  \
    F(8)  F(9)  F(10) F(11) F(12) F(13) F(14) F(15) \
    F(16) F(17) F(18) F(19) F(20) F(21) F(22) F(23) \
    F(24) F(25) F(26) F(27) F(28) F(29) F(30) F(31) \
    F(32) F(33) F(34) F(35) F(36) F(37) F(38) F(39) \
    F(40) F(41) F(42) F(43) F(44) F(45) F(46) F(47) \
    F(48) F(49) F(50) F(51) F(52) F(53) F(54) F(55) \
    F(56) F(57) F(58) F(59) F(60) F(61) F(62) F(63)

// one FMA line: dim K -> bank vreg VR, chain v(81 + K%4).
// First 4 dims (quarter 0) are v_mul == fmaf(z,e,+0) (only a -0/+0 sign
// difference, cannot affect the summed partials or the compare).
#define MULQ(ACC, ZI, VR) "v_mul_f32 v" #ACC ", %[z" #ZI "], v" #VR "\n\t"
#define FMAQ(ACC, ZI, VR) "v_fma_f32 v" #ACC ", %[z" #ZI "], v" #VR ", v" #ACC "\n\t"

// ---- argmin over a 128-code chunk, one thread per token -------------------
// grid = 8192 blocks: block = (tokenBlock<<5) | chunk
// r10 post-mortem: 69.6KB LDS -> 2 waves/SIMD and a full lgkmcnt(0) drain of
// 17 ds_reads per iter -> ~60% latency stall. Fix: (1) CPC=128 -> 34.9KB LDS
// -> 4 blocks/CU = 4 waves/SIMD; (2) quarter-granular double-buffered
// pipeline with counted lgkmcnt(4/5) waits (DS ops are in-order per wave, so
// partial waits are exact — unlike SMEM). 8-9 reads stay outstanding; next
// row's first quarter issues before this row's last FMA burst.
__global__ __launch_bounds__(256, 4) void kArgmin(const float* __restrict__ z,
                                                  const float* __restrict__ aug,
                                                  unsigned long long* __restrict__ packed) {
    __shared__ alignas(16) float lds[CPC * 68 + 16];   // 34,880 B (incl. OOB pad)
    int bid = blockIdx.x;
    int tb = bid >> 5;
    int chunk = bid & 31;

    // stage this chunk's aug rows into LDS (34,816B contiguous, f32x2 copy:
    // 4352 pairs / 256 threads = 17 each, coalesced)
    {
        const f32x2* src = (const f32x2*)(aug + (long)(chunk * CPC) * 68);
        f32x2* dst = (f32x2*)lds;
#pragma unroll
        for (int i = 0; i < 17; ++i)
            dst[threadIdx.x + i * 256] = src[threadIdx.x + i * 256];
    }
    __syncthreads();

    int t = tb * 256 + threadIdx.x;             // token id
    int b = t >> 14;                            // batch
    int s = t & 16383;                          // d*1024+h*32+w
    const float* zp = z + (long)b * 1048576 + s;

#define Z_LOAD(J) float Z##J = zp[J * 16384];
    Z_EACH(Z_LOAD)
#undef Z_LOAD

    // A = sum z^2: the reference 4-partial fmaf chain (bit-identical)
    float a0 = 0.f, a1 = 0.f, a2 = 0.f, a3 = 0.f;
#define Z_ASUM(J) { if ((J & 3) == 0) a0 = fmaf(Z##J, Z##J, a0); \
                    else if ((J & 3) == 1) a1 = fmaf(Z##J, Z##J, a1); \
                    else if ((J & 3) == 2) a2 = fmaf(Z##J, Z##J, a2); \
                    else a3 = fmaf(Z##J, Z##J, a3); }
    Z_EACH(Z_ASUM)
#undef Z_ASUM
    float A = (a0 + a1) + (a2 + a3);

    int c0i = chunk * CPC;
    float best = __builtin_inff();
    int bidx = c0i;
    // LDS byte offset of lds[0]: low 32 bits of the generic pointer are the
    // LDS offset (4GiB-aligned shared aperture) — proven in r10.
    unsigned va0 = (unsigned)(unsigned long long)(&lds[0]);

    // Banks: A = v[48:63], B = v[64:79]; bq v80; chains v81-84 (= d0..d3,
    // dim k -> chain k%4, ascending — bit-identical to the r10 passing loop);
    // tmp v85-86; idx counter v87. Row stride 272B; 128 iters.
    asm volatile(
        "s_mov_b32 s32, 0\n\t"
        "v_mov_b32 v87, %[n0]\n\t"
        "ds_read_b128 v[48:51], %[va] offset:0\n\t"    // Q0 row0 -> A
        "ds_read_b128 v[52:55], %[va] offset:16\n\t"
        "ds_read_b128 v[56:59], %[va] offset:32\n\t"
        "ds_read_b128 v[60:63], %[va] offset:48\n\t"
        "1:\n\t"
        "ds_read_b128 v[64:67], %[va] offset:64\n\t"   // Q1 -> B
        "ds_read_b128 v[68:71], %[va] offset:80\n\t"
        "ds_read_b128 v[72:75], %[va] offset:96\n\t"
        "ds_read_b128 v[76:79], %[va] offset:112\n\t"
        "s_waitcnt lgkmcnt(4)\n\t"                     // Q0 ready
        MULQ(81, 0, 48) MULQ(82, 1, 49) MULQ(83, 2, 50) MULQ(84, 3, 51)
        FMAQ(81, 4, 52) FMAQ(82, 5, 53) FMAQ(83, 6, 54) FMAQ(84, 7, 55)
        FMAQ(81, 8, 56) FMAQ(82, 9, 57) FMAQ(83, 10, 58) FMAQ(84, 11, 59)
        FMAQ(81, 12, 60) FMAQ(82, 13, 61) FMAQ(83, 14, 62) FMAQ(84, 15, 63)
        "ds_read_b128 v[48:51], %[va] offset:128\n\t"  // Q2 -> A
        "ds_read_b128 v[52:55], %[va] offset:144\n\t"
        "ds_read_b128 v[56:59], %[va] offset:160\n\t"
        "ds_read_b128 v[60:63], %[va] offset:176\n\t"
        "s_waitcnt lgkmcnt(4)\n\t"                     // Q1 ready
        FMAQ(81, 16, 64) FMAQ(82, 17, 65) FMAQ(83, 18, 66) FMAQ(84, 19, 67)
        FMAQ(81, 20, 68) FMAQ(82, 21, 69) FMAQ(83, 22, 70) FMAQ(84, 23, 71)
        FMAQ(81, 24, 72) FMAQ(82, 25, 73) FMAQ(83, 26, 74) FMAQ(84, 27, 75)
        FMAQ(81, 28, 76) FMAQ(82, 29, 77) FMAQ(83, 30, 78) FMAQ(84, 31, 79)
        "ds_read_b128 v[64:67], %[va] offset:192\n\t"  // Q3 -> B, + bq
        "ds_read_b128 v[68:71], %[va] offset:208\n\t"
        "ds_read_b128 v[72:75], %[va] offset:224\n\t"
        "ds_read_b128 v[76:79], %[va] offset:240\n\t"
        "ds_read_b32 v80, %[va] offset:256\n\t"
        "s_waitcnt lgkmcnt(5)\n\t"                     // Q2 ready
        FMAQ(81, 32, 48) FMAQ(82, 33, 49) FMAQ(83, 34, 50) FMAQ(84, 35, 51)
        FMAQ(81, 36, 52) FMAQ(82, 37, 53) FMAQ(83, 38, 54) FMAQ(84, 39, 55)
        FMAQ(81, 40, 56) FMAQ(82, 41, 57) FMAQ(83, 42, 58) FMAQ(84, 43, 59)
        FMAQ(81, 44, 60) FMAQ(82, 45, 61) FMAQ(83, 46, 62) FMAQ(84, 47, 63)
        "v_add_u32 %[va], 0x110, %[va]\n\t"            // next row
        "ds_read_b128 v[48:51], %[va] offset:0\n\t"    // next Q0 -> A
        "ds_read_b128 v[52:55], %[va] offset:16\n\t"
        "ds_read_b128 v[56:59], %[va] offset:32\n\t"
        "ds_read_b128 v[60:63], %[va] offset:48\n\t"
        "s_waitcnt lgkmcnt(4)\n\t"                     // Q3 + bq ready
        FMAQ(81, 48, 64) FMAQ(82, 49, 65) FMAQ(83, 50, 66) FMAQ(84, 51, 67)
        FMAQ(81, 52, 68) FMAQ(82, 53, 69) FMAQ(83, 54, 70) FMAQ(84, 55, 71)
        FMAQ(81, 56, 72) FMAQ(82, 57, 73) FMAQ(83, 58, 74) FMAQ(84, 59, 75)
        FMAQ(81, 60, 76) FMAQ(82, 61, 77) FMAQ(83, 62, 78) FMAQ(84, 63, 79)
        "v_add_f32 v85, v81, v82\n\t"
        "v_add_f32 v86, v83, v84\n\t"
        "v_add_f32 v85, v85, v86\n\t"
        "v_add_f32 v86, v80, %[A]\n\t"
        "v_fma_f32 v85, -2.0, v85, v86\n\t"
        "v_cmp_lt_f32 vcc, v85, %[best]\n\t"
        "v_cndmask_b32 %[best], %[best], v85, vcc\n\t"
        "v_cndmask_b32 %[bidx], %[bidx], v87, vcc\n\t"
        "v_add_u32 v87, 1, v87\n\t"
        "s_add_u32 s32, s32, 1\n\t"
        "s_cmp_lt_u32 s32, 0x80\n\t"
        "s_cbranch_scc1 1b\n\t"
        "s_waitcnt lgkmcnt(0)\n\t"                     // drain dangling Q0
        : [best]"+v"(best), [bidx]"+v"(bidx), [va]"+v"(va0)
        : [z0]"v"(Z0),  [z1]"v"(Z1),  [z2]"v"(Z2),  [z3]"v"(Z3),
          [z4]"v"(Z4),  [z5]"v"(Z5),  [z6]"v"(Z6),  [z7]"v"(Z7),
          [z8]"v"(Z8),  [z9]"v"(Z9),  [z10]"v"(Z10), [z11]"v"(Z11),
          [z12]"v"(Z12), [z13]"v"(Z13), [z14]"v"(Z14), [z15]"v"(Z15),
          [z16]"v"(Z16), [z17]"v"(Z17), [z18]"v"(Z18), [z19]"v"(Z19),
          [z20]"v"(Z20), [z21]"v"(Z21), [z22]"v"(Z22), [z23]"v"(Z23),
          [z24]"v"(Z24), [z25]"v"(Z25), [z26]"v"(Z26), [z27]"v"(Z27),
          [z28]"v"(Z28), [z29]"v"(Z29), [z30]"v"(Z30), [z31]"v"(Z31),
          [z32]"v"(Z32), [z33]"v"(Z33), [z34]"v"(Z34), [z35]"v"(Z35),
          [z36]"v"(Z36), [z37]"v"(Z37), [z38]"v"(Z38), [z39]"v"(Z39),
          [z40]"v"(Z40), [z41]"v"(Z41), [z42]"v"(Z42), [z43]"v"(Z43),
          [z44]"v"(Z44), [z45]"v"(Z45), [z46]"v"(Z46), [z47]"v"(Z47),
          [z48]"v"(Z48), [z49]"v"(Z49), [z50]"v"(Z50), [z51]"v"(Z51),
          [z52]"v"(Z52), [z53]"v"(Z53), [z54]"v"(Z54), [z55]"v"(Z55),
          [z56]"v"(Z56), [z57]"v"(Z57), [z58]"v"(Z58), [z59]"v"(Z59),
          [z60]"v"(Z60), [z61]"v"(Z61), [z62]"v"(Z62), [z63]"v"(Z63),
          [A]"v"(A), [n0]"v"(c0i)
        : "s32",
          "v48","v49","v50","v51","v52","v53","v54","v55",
          "v56","v57","v58","v59","v60","v61","v62","v63",
          "v64","v65","v66","v67","v68","v69","v70","v71",
          "v72","v73","v74","v75","v76","v77","v78","v79",
          "v80","v81","v82","v83","v84","v85","v86","v87",
          "vcc","scc","memory");

    // d >= 0 always so float order == uint order; low 32 bits = idx so
    // equal-d ties pick the smaller index (first-occurrence argmin).
    unsigned long long pk =
        ((unsigned long long)__float_as_uint(best) << 32) | (unsigned)bidx;
    atomicMin(&packed[t], pk);
}

// ---- unpack chunk-combined argmin, emit idx + counts ----------------------
__global__ __launch_bounds__(256) void kFinish(const unsigned long long* __restrict__ packed,
                                               float* __restrict__ outIdxF,
                                               int* __restrict__ wsIdx,
                                               unsigned* __restrict__ counts) {
    int t = blockIdx.x * 256 + threadIdx.x;
    int idx = (int)(unsigned)(packed[t] & 0xFFFFFFFFull);
    outIdxF[t] = (float)idx;
    wsIdx[t]   = idx;
    atomicAdd(&counts[idx], 1u);
}

// ---- exclusive prefix sum of counts -> bucket offsets ---------------------
__global__ __launch_bounds__(256) void kOffsets(const unsigned* __restrict__ counts,
                                                unsigned* __restrict__ offsets) {
    __shared__ unsigned psum[256];
    int tid = threadIdx.x;
    unsigned local[16];
    unsigned s = 0;
#pragma unroll
    for (int j = 0; j < 16; ++j) { local[j] = s; s += counts[tid * 16 + j]; }
    psum[tid] = s;
    __syncthreads();
    unsigned base = 0;
    for (int i = 0; i < tid; ++i) base += psum[i];
#pragma unroll
    for (int j = 0; j < 16; ++j) offsets[tid * 16 + j] = base + local[j];
}

// ---- scatter token ids into per-code buckets ------------------------------
__global__ __launch_bounds__(256) void kScatter(const int* __restrict__ wsIdx,
                                                const unsigned* __restrict__ offsets,
                                                unsigned* __restrict__ cursor,
                                                int* __restrict__ bucket) {
    int t = blockIdx.x * 256 + threadIdx.x;
    int idx = wsIdx[t];
    unsigned pos = atomicAdd(&cursor[idx], 1u);
    bucket[offsets[idx] + pos] = t;
}

// ---- streaming epilogue: gather, straight-through out, loss partials ------
__global__ __launch_bounds__(256) void kEpilogue(const float* __restrict__ z,
                                                 const float* __restrict__ e,
                                                 const int* __restrict__ wsIdx,
                                                 float* __restrict__ out,
                                                 double* __restrict__ lossPart) {
    __shared__ double lp[4];
    long g = (long)blockIdx.x * 256 + threadIdx.x;   // 0 .. 4194303 (z-linear)
    int b = (int)(g >> 20);
    int r = (int)(g & 1048575);
    int k = r >> 14;
    int s = r & 16383;
    int t = (b << 14) | s;

    float zv = z[g];
    int n = wsIdx[t];
    float eq = e[(n << 6) + k];
    float diff = eq - zv;            // fl(z_q - zp)
    out[g] = zv + diff;              // fl(zp + fl(z_q - zp))  (straight-through)

    double sq = (double)diff * (double)diff;
#pragma unroll
    for (int o = 32; o > 0; o >>= 1) sq += __shfl_down(sq, o);
    if ((threadIdx.x & 63) == 0) lp[threadIdx.x >> 6] = sq;
    __syncthreads();
    if (threadIdx.x == 0) lossPart[blockIdx.x] = (lp[0] + lp[1]) + (lp[2] + lp[3]);
}

// ---- reduce loss partials -------------------------------------------------
__global__ __launch_bounds__(256) void kLoss(const double* __restrict__ lossPart,
                                             double* __restrict__ acc) {
    __shared__ double lp[4];
    double s = 0.0;
    for (int j = 0; j < 64; ++j) s += lossPart[threadIdx.x + j * 256];
#pragma unroll
    for (int o = 32; o > 0; o >>= 1) s += __shfl_down(s, o);
    if ((threadIdx.x & 63) == 0) lp[threadIdx.x >> 6] = s;
    __syncthreads();
    if (threadIdx.x == 0) acc[0] = (lp[0] + lp[1]) + (lp[2] + lp[3]);
}

// ---- EMA part 1: new_cs, n-sum, perplexity partial ------------------------
__global__ __launch_bounds__(256) void kEma1(const float* __restrict__ cs,
                                             const unsigned* __restrict__ counts,
                                             float* __restrict__ outNcs,
                                             double* __restrict__ acc) {
    int n = blockIdx.x * 256 + threadIdx.x;
    float cf = (float)counts[n];
    float p1 = cs[n] * 0.99f;
    float p2 = 0.01f * cf;
    float ncs = p1 + p2;
    outNcs[n] = ncs;
    float p = cf * (1.0f / 65536.0f);          // exact (pow2 divide)
    float term = p * logf(p + 1e-10f);
    double dn = (double)ncs, dt = (double)term;
#pragma unroll
    for (int o = 32; o > 0; o >>= 1) { dn += __shfl_down(dn, o); dt += __shfl_down(dt, o); }
    if ((threadIdx.x & 63) == 0) {
        atomicAdd(&acc[1], dn);
        atomicAdd(&acc[2], dt);
    }
}

// ---- per-code bucket gather: embed_sum -> new_ea, new_embed; scalars ------
__global__ __launch_bounds__(64) void kEsumEma2(const float* __restrict__ z,
                                                const float* __restrict__ ea,
                                                const int* __restrict__ bucket,
                                                const unsigned* __restrict__ offsets,
                                                const unsigned* __restrict__ counts,
                                                const float* __restrict__ ncsArr,
                                                const double* __restrict__ acc,
                                                float* __restrict__ outNemb,
                                                float* __restrict__ outNea,
                                                float* __restrict__ outLoss,
                                                float* __restrict__ outPerp) {
    int n = blockIdx.x;              // code id
    int k = threadIdx.x;             // dim
    unsigned off = offsets[n];
    unsigned cnt = counts[n];
    float es = 0.f;
    for (unsigned i = 0; i < cnt; ++i) {
        int t = bucket[off + i];
        int b = t >> 14;
        int s = t & 16383;
        es += z[(long)b * 1048576 + k * 16384 + s];
    }
    float nea = ea[(n << 6) + k] * 0.99f + 0.01f * es;
    outNea[(n << 6) + k] = nea;
    float nt = (float)acc[1];
    float ncs = ncsArr[n];
    float sc = ((ncs + 1e-5f) / (nt + 0.04096f)) * nt;
    outNemb[(n << 6) + k] = nea / sc;
    if (n == 0 && k == 0) {
        double m = acc[0] / 4194304.0;
        outLoss[0] = 0.25f * (float)m;
        outPerp[0] = (float)exp(-acc[2]);
    }
}

extern "C" void kernel_launch(void* const* d_in, const int* in_sizes, int n_in,
                              void* d_out, int out_size, void* d_ws, size_t ws_size,
                              hipStream_t stream) {
    const float* z  = (const float*)d_in[0];
    const float* ew = (const float*)d_in[1];
    const float* cs = (const float*)d_in[2];
    const float* ea = (const float*)d_in[3];
    float* out = (float*)d_out;
    char* ws = (char*)d_ws;

    double*   acc    = (double*)(ws + W_ACC);
    unsigned* counts = (unsigned*)(ws + W_CNT);
    unsigned* cursor = (unsigned*)(ws + W_CUR);
    unsigned* offs   = (unsigned*)(ws + W_OFF);
    int*      wsIdx  = (int*)(ws + W_IDX);
    int*      bucket = (int*)(ws + W_BKT);
    double*   lossP  = (double*)(ws + W_LOSSP);
    unsigned long long* packed = (unsigned long long*)(ws + W_PKD);
    float*    aug    = (float*)(ws + W_AUG);

    hipMemsetAsync(ws, 0, W_ZERO_BYTES, stream);
    hipMemsetAsync(ws + W_PKD, 0xFF, W_PKD_BYTES, stream);
    kAug<<<NE / 256, 256, 0, stream>>>(ew, aug);
    kArgmin<<<(NTOK / 256) * NCHUNK, 256, 0, stream>>>(z, aug, packed);
    kFinish<<<NTOK / 256, 256, 0, stream>>>(packed, out + O_IDX, wsIdx, counts);
    kOffsets<<<1, 256, 0, stream>>>(counts, offs);
    kScatter<<<NTOK / 256, 256, 0, stream>>>(wsIdx, offs, cursor, bucket);
    kEpilogue<<<16384, 256, 0, stream>>>(z, ew, wsIdx, out + O_OUT, lossP);
    kLoss<<<1, 256, 0, stream>>>(lossP, acc);
    kEma1<<<NE / 256, 256, 0, stream>>>(cs, counts, out + O_NCS, acc);
    kEsumEma2<<<NE, 64, 0, stream>>>(z, ea, bucket, offs, counts, out + O_NCS, acc,
                                     out + O_NEMB, out + O_NEA,
                                     out + O_LOSS, out + O_PERP);
}

// Round 12
// 576.107 us; speedup vs baseline: 1.1628x; 1.1628x over previous
//
#include <hip/hip_runtime.h>

static constexpr int NE   = 4096;      // n_embed
static constexpr int ED   = 64;        // embed_dim
static constexpr int NTOK = 65536;     // 4*16*32*32
static constexpr int NCHUNK = 32;      // code-loop split factor
static constexpr int CPC  = NE / NCHUNK;   // codes per chunk = 128

typedef float  f32x2 __attribute__((ext_vector_type(2)));
typedef float  f32x4 __attribute__((ext_vector_type(4)));

// d_out offsets (float elements), outputs concatenated in return order:
// out(4194304), loss(1), perplexity(1), idx(65536), new_embed(262144),
// new_cs(4096), new_ea(262144)
static constexpr long O_OUT  = 0;
static constexpr long O_LOSS = 4194304;
static constexpr long O_PERP = 4194305;
static constexpr long O_IDX  = 4194306;
static constexpr long O_NEMB = 4259842;
static constexpr long O_NCS  = 4521986;
static constexpr long O_NEA  = 4526082;

// ws layout (bytes)
static constexpr size_t W_ACC   = 0;        // double[4]: [0]=loss [1]=n [2]=plog   (zeroed)
static constexpr size_t W_CNT   = 32;       // unsigned[4096] counts                (zeroed)
static constexpr size_t W_CUR   = 16416;    // unsigned[4096] scatter cursors       (zeroed)
static constexpr size_t W_OFF   = 32800;    // unsigned[4096] bucket start offsets
static constexpr size_t W_IDX   = 49184;    // int[65536]
static constexpr size_t W_BKT   = 311328;   // int[65536] token ids bucketed by code
static constexpr size_t W_LOSSP = 573472;   // double[16384] per-block loss partials
static constexpr size_t W_PKD   = 704544;   // uint64[65536] packed (d_bits<<32)|idx
static constexpr size_t W_AUG   = 1228832;  // float[4096*68]: [e row (64), bq, pad(3)]
static constexpr size_t W_ZERO_BYTES = 32800;   // acc + counts + cursors
static constexpr size_t W_PKD_BYTES  = 524288;  // 0xFF-init packed

// ---- augmented codebook: row n = [e_n[0..63], ||e_n||^2, pad] (stride 68) --
__global__ __launch_bounds__(256) void kAug(const float* __restrict__ e,
                                            float* __restrict__ aug) {
    int n = blockIdx.x * 256 + threadIdx.x;        // 0..4095
    const float* er = e + (n << 6);
    float* row = aug + (long)n * 68;
    // bq numerics: identical fmaf 4-partial chain to the 11x-passing kBsq
    float a0 = 0.f, a1 = 0.f, a2 = 0.f, a3 = 0.f;
#pragma unroll
    for (int k = 0; k < ED; k += 4) {
        a0 = fmaf(er[k+0], er[k+0], a0);
        a1 = fmaf(er[k+1], er[k+1], a1);
        a2 = fmaf(er[k+2], er[k+2], a2);
        a3 = fmaf(er[k+3], er[k+3], a3);
    }
#pragma unroll
    for (int k = 0; k < 16; ++k)
        ((f32x4*)row)[k] = ((const f32x4*)er)[k];
    row[64] = (a0 + a1) + (a2 + a3);
}

// ---- asm text helper macros ------------------------------------------------
// z load: dest VGPR, addr = v233 (bumped 0x10000 = one dim stride)
#define ZLD(VD) \
    "global_load_dword v" #VD ", v233, %[zb]\n\t" \
    "v_add_u32 v233, 0x10000, v233\n\t"
// A-sum lines (chain C, z-reg Z): fl(z*z) / fl(z*z + c)
#define AMUL(C, Z) "v_mul_f32 v" #C ", v" #Z ", v" #Z "\n\t"
#define AFMA(C, Z) "v_fma_f32 v" #C ", v" #Z ", v" #Z ", v" #C "\n\t"
#define AQ4(Z0,Z1,Z2,Z3) AFMA(225,Z0) AFMA(226,Z1) AFMA(227,Z2) AFMA(228,Z3)
#define BQ4(Z0,Z1,Z2,Z3) AFMA(229,Z0) AFMA(230,Z1) AFMA(231,Z2) AFMA(232,Z3)
// dot lines: token0 chain CA (z ZA), token1 chain CB (z ZB), shared e-reg E
#define M2(CA,CB,ZA,ZB,E) \
    "v_mul_f32 v" #CA ", v" #ZA ", v" #E "\n\t" \
    "v_mul_f32 v" #CB ", v" #ZB ", v" #E "\n\t"
#define D2(CA,CB,ZA,ZB,E) \
    "v_fma_f32 v" #CA ", v" #ZA ", v" #E ", v" #CA "\n\t" \
    "v_fma_f32 v" #CB ", v" #ZB ", v" #E ", v" #CB "\n\t"

// ---- argmin over a 128-code chunk, TWO tokens per thread -------------------
// grid = 4096 blocks: block = (tokenBlock<<5) | chunk; tokens t0 = tb*512+tid,
// t1 = t0+256 (same batch: 16384 % 512 == 0).
// r11 post-mortem: LDS-return-BW bound — broadcast ds_read_b128 still writes
// 64 lanes x 16B; 71M DS insts x ~5.2cyc/CU == the measured 604us. Fix:
// register-tile T=2 tokens/thread so 17 ds_reads feed 128 FMAs (DS per FMA
// halved). z loaded inside asm into fixed v[64:191] via 32-bit voffset +
// SGPR base; VGPR budget ~240 -> 2 waves/SIMD (BW-bound, TLP less critical).
// Fixed regs: v[64:127] z-tok0, v[128:191] z-tok1, v[192:207] bankA,
// v[208:223] bankB, v224 bq, v225-228 chains t0, v229-232 chains t1,
// v233/v236 tmps, v234 A0, v235 A1, v237 idx counter.
__global__ __launch_bounds__(256, 2) void kArgmin(const float* __restrict__ z,
                                                  const float* __restrict__ aug,
                                                  unsigned long long* __restrict__ packed) {
    __shared__ alignas(16) float lds[CPC * 68 + 16];   // 34,880 B (incl. OOB pad)
    int bid = blockIdx.x;
    int tb = bid >> 5;
    int chunk = bid & 31;

    // stage this chunk's aug rows into LDS (34,816B contiguous, f32x2 copy)
    {
        const f32x2* src = (const f32x2*)(aug + (long)(chunk * CPC) * 68);
        f32x2* dst = (f32x2*)lds;
#pragma unroll
        for (int i = 0; i < 17; ++i)
            dst[threadIdx.x + i * 256] = src[threadIdx.x + i * 256];
    }
    __syncthreads();

    int t0 = tb * 512 + threadIdx.x;            // token 0
    int t1 = t0 + 256;                          // token 1 (same batch)
    int b  = t0 >> 14;
    int s0 = t0 & 16383;
    unsigned off0 = ((unsigned)b * 1048576u + (unsigned)s0) * 4u;  // byte offset
    unsigned off1 = off0 + 1024u;               // +256 tokens * 4B

    int c0i = chunk * CPC;
    float best0 = __builtin_inff(), best1 = __builtin_inff();
    int bidx0 = c0i, bidx1 = c0i;
    // LDS byte offset of lds[0]: low 32 bits of the generic pointer are the
    // LDS offset (proven r10/r11).
    unsigned va0 = (unsigned)(unsigned long long)(&lds[0]);

    asm volatile(
        // ---- prologue: load z for both tokens (dim stride 0x10000 B) ----
        "v_mov_b32 v233, %[off0]\n\t"
        ZLD(64)  ZLD(65)  ZLD(66)  ZLD(67)  ZLD(68)  ZLD(69)  ZLD(70)  ZLD(71)
        ZLD(72)  ZLD(73)  ZLD(74)  ZLD(75)  ZLD(76)  ZLD(77)  ZLD(78)  ZLD(79)
        ZLD(80)  ZLD(81)  ZLD(82)  ZLD(83)  ZLD(84)  ZLD(85)  ZLD(86)  ZLD(87)
        ZLD(88)  ZLD(89)  ZLD(90)  ZLD(91)  ZLD(92)  ZLD(93)  ZLD(94)  ZLD(95)
        ZLD(96)  ZLD(97)  ZLD(98)  ZLD(99)  ZLD(100) ZLD(101) ZLD(102) ZLD(103)
        ZLD(104) ZLD(105) ZLD(106) ZLD(107) ZLD(108) ZLD(109) ZLD(110) ZLD(111)
        ZLD(112) ZLD(113) ZLD(114) ZLD(115) ZLD(116) ZLD(117) ZLD(118) ZLD(119)
        ZLD(120) ZLD(121) ZLD(122) ZLD(123) ZLD(124) ZLD(125) ZLD(126) ZLD(127)
        "v_mov_b32 v233, %[off1]\n\t"
        ZLD(128) ZLD(129) ZLD(130) ZLD(131) ZLD(132) ZLD(133) ZLD(134) ZLD(135)
        ZLD(136) ZLD(137) ZLD(138) ZLD(139) ZLD(140) ZLD(141) ZLD(142) ZLD(143)
        ZLD(144) ZLD(145) ZLD(146) ZLD(147) ZLD(148) ZLD(149) ZLD(150) ZLD(151)
        ZLD(152) ZLD(153) ZLD(154) ZLD(155) ZLD(156) ZLD(157) ZLD(158) ZLD(159)
        ZLD(160) ZLD(161) ZLD(162) ZLD(163) ZLD(164) ZLD(165) ZLD(166) ZLD(167)
        ZLD(168) ZLD(169) ZLD(170) ZLD(171) ZLD(172) ZLD(173) ZLD(174) ZLD(175)
        ZLD(176) ZLD(177) ZLD(178) ZLD(179) ZLD(180) ZLD(181) ZLD(182) ZLD(183)
        ZLD(184) ZLD(185) ZLD(186) ZLD(187) ZLD(188) ZLD(189) ZLD(190) ZLD(191)
        "s_waitcnt vmcnt(0)\n\t"
        // ---- A0 = sum z0^2 (reference 4-partial chain, ascending) ----
        AMUL(225,64) AMUL(226,65) AMUL(227,66) AMUL(228,67)
        AQ4(68,69,70,71)    AQ4(72,73,74,75)    AQ4(76,77,78,79)
        AQ4(80,81,82,83)    AQ4(84,85,86,87)    AQ4(88,89,90,91)
        AQ4(92,93,94,95)    AQ4(96,97,98,99)    AQ4(100,101,102,103)
        AQ4(104,105,106,107) AQ4(108,109,110,111) AQ4(112,113,114,115)
        AQ4(116,117,118,119) AQ4(120,121,122,123) AQ4(124,125,126,127)
        "v_add_f32 v234, v225, v226\n\t"
        "v_add_f32 v233, v227, v228\n\t"
        "v_add_f32 v234, v234, v233\n\t"          // A0
        // ---- A1 = sum z1^2 ----
        AMUL(229,128) AMUL(230,129) AMUL(231,130) AMUL(232,131)
        BQ4(132,133,134,135) BQ4(136,137,138,139) BQ4(140,141,142,143)
        BQ4(144,145,146,147) BQ4(148,149,150,151) BQ4(152,153,154,155)
        BQ4(156,157,158,159) BQ4(160,161,162,163) BQ4(164,165,166,167)
        BQ4(168,169,170,171) BQ4(172,173,174,175) BQ4(176,177,178,179)
        BQ4(180,181,182,183) BQ4(184,185,186,187) BQ4(188,189,190,191)
        "v_add_f32 v235, v229, v230\n\t"
        "v_add_f32 v233, v231, v232\n\t"
        "v_add_f32 v235, v235, v233\n\t"          // A1
        // ---- loop setup + Q0 preload ----
        "s_mov_b32 s32, 0\n\t"
        "v_mov_b32 v237, %[n0]\n\t"
        "ds_read_b128 v[192:195], %[va] offset:0\n\t"
        "ds_read_b128 v[196:199], %[va] offset:16\n\t"
        "ds_read_b128 v[200:203], %[va] offset:32\n\t"
        "ds_read_b128 v[204:207], %[va] offset:48\n\t"
        "1:\n\t"
        "ds_read_b128 v[208:211], %[va] offset:64\n\t"   // Q1 -> B
        "ds_read_b128 v[212:215], %[va] offset:80\n\t"
        "ds_read_b128 v[216:219], %[va] offset:96\n\t"
        "ds_read_b128 v[220:223], %[va] offset:112\n\t"
        "s_waitcnt lgkmcnt(4)\n\t"                       // Q0 (A) ready
        M2(225,229,64,128,192) M2(226,230,65,129,193)
        M2(227,231,66,130,194) M2(228,232,67,131,195)
        D2(225,229,68,132,196) D2(226,230,69,133,197)
        D2(227,231,70,134,198) D2(228,232,71,135,199)
        D2(225,229,72,136,200) D2(226,230,73,137,201)
        D2(227,231,74,138,202) D2(228,232,75,139,203)
        D2(225,229,76,140,204) D2(226,230,77,141,205)
        D2(227,231,78,142,206) D2(228,232,79,143,207)
        "ds_read_b128 v[192:195], %[va] offset:128\n\t"  // Q2 -> A
        "ds_read_b128 v[196:199], %[va] offset:144\n\t"
        "ds_read_b128 v[200:203], %[va] offset:160\n\t"
        "ds_read_b128 v[204:207], %[va] offset:176\n\t"
        "s_waitcnt lgkmcnt(4)\n\t"                       // Q1 (B) ready
        D2(225,229,80,144,208) D2(226,230,81,145,209)
        D2(227,231,82,146,210) D2(228,232,83,147,211)
        D2(225,229,84,148,212) D2(226,230,85,149,213)
        D2(227,231,86,150,214) D2(228,232,87,151,215)
        D2(225,229,88,152,216) D2(226,230,89,153,217)
        D2(227,231,90,154,218) D2(228,232,91,155,219)
        D2(225,229,92,156,220) D2(226,230,93,157,221)
        D2(227,231,94,158,222) D2(228,232,95,159,223)
        "ds_read_b128 v[208:211], %[va] offset:192\n\t"  // Q3 -> B, + bq
        "ds_read_b128 v[212:215], %[va] offset:208\n\t"
        "ds_read_b128 v[216:219], %[va] offset:224\n\t"
        "ds_read_b128 v[220:223], %[va] offset:240\n\t"
        "ds_read_b32 v224, %[va] offset:256\n\t"
        "s_waitcnt lgkmcnt(5)\n\t"                       // Q2 (A) ready
        D2(225,229,96,160,192)  D2(226,230,97,161,193)
        D2(227,231,98,162,194)  D2(228,232,99,163,195)
        D2(225,229,100,164,196) D2(226,230,101,165,197)
        D2(227,231,102,166,198) D2(228,232,103,167,199)
        D2(225,229,104,168,200) D2(226,230,105,169,201)
        D2(227,231,106,170,202) D2(228,232,107,171,203)
        D2(225,229,108,172,204) D2(226,230,109,173,205)
        D2(227,231,110,174,206) D2(228,232,111,175,207)
        "v_add_u32 %[va], 0x110, %[va]\n\t"              // next row
        "ds_read_b128 v[192:195], %[va] offset:0\n\t"    // next Q0 -> A
        "ds_read_b128 v[196:199], %[va] offset:16\n\t"
        "ds_read_b128 v[200:203], %[va] offset:32\n\t"
        "ds_read_b128 v[204:207], %[va] offset:48\n\t"
        "s_waitcnt lgkmcnt(4)\n\t"                       // Q3 + bq ready
        D2(225,229,112,176,208) D2(226,230,113,177,209)
        D2(227,231,114,178,210) D2(228,232,115,179,211)
        D2(225,229,116,180,212) D2(226,230,117,181,213)
        D2(227,231,118,182,214) D2(228,232,119,183,215)
        D2(225,229,120,184,216) D2(226,230,121,185,217)
        D2(227,231,122,186,218) D2(228,232,123,187,219)
        D2(225,229,124,188,220) D2(226,230,125,189,221)
        D2(227,231,126,190,222) D2(228,232,127,191,223)
        // ---- tails: d = fl((A+bq) - 2*dot), strict-< min track ----
        "v_add_f32 v233, v225, v226\n\t"
        "v_add_f32 v236, v227, v228\n\t"
        "v_add_f32 v233, v233, v236\n\t"
        "v_add_f32 v236, v224, v234\n\t"
        "v_fma_f32 v233, -2.0, v233, v236\n\t"
        "v_cmp_lt_f32 vcc, v233, %[best0]\n\t"
        "v_cndmask_b32 %[best0], %[best0], v233, vcc\n\t"
        "v_cndmask_b32 %[bidx0], %[bidx0], v237, vcc\n\t"
        "v_add_f32 v233, v229, v230\n\t"
        "v_add_f32 v236, v231, v232\n\t"
        "v_add_f32 v233, v233, v236\n\t"
        "v_add_f32 v236, v224, v235\n\t"
        "v_fma_f32 v233, -2.0, v233, v236\n\t"
        "v_cmp_lt_f32 vcc, v233, %[best1]\n\t"
        "v_cndmask_b32 %[best1], %[best1], v233, vcc\n\t"
        "v_cndmask_b32 %[bidx1], %[bidx1], v237, vcc\n\t"
        "v_add_u32 v237, 1, v237\n\t"
        "s_add_u32 s32, s32, 1\n\t"
        "s_cmp_lt_u32 s32, 0x80\n\t"
        "s_cbranch_scc1 1b\n\t"
        "s_waitcnt lgkmcnt(0)\n\t"                       // drain dangling Q0
        : [best0]"+v"(best0), [bidx0]"+v"(bidx0),
          [best1]"+v"(best1), [bidx1]"+v"(bidx1), [va]"+v"(va0)
        : [zb]"s"(z), [off0]"v"(off0), [off1]"v"(off1), [n0]"v"(c0i)
        : "s32",
          "v64","v65","v66","v67","v68","v69","v70","v71",
          "v72","v73","v74","v75","v76","v77","v78","v79",
          "v80","v81","v82","v83","v84","v85","v86","v87",
          "v88","v89","v90","v91","v92","v93","v94","v95",
          "v96","v97","v98","v99","v100","v101","v102","v103",
          "v104","v105","v106","v107","v108","v109","v110","v111",
          "v112","v113","v114","v115","v116","v117","v118","v119",
          "v120","v121","v122","v123","v124","v125","v126","v127",
          "v128","v129","v130","v131","v132","v133","v134","v135",
          "v136","v137","v138","v139","v140","v141","v142","v143",
          "v144","v145","v146","v147","v148","v149","v150","v151",
          "v152","v153","v154","v155","v156","v157","v158","v159",
          "v160","v161","v162","v163","v164","v165","v166","v167",
          "v168","v169","v170","v171","v172","v173","v174","v175",
          "v176","v177","v178","v179","v180","v181","v182","v183",
          "v184","v185","v186","v187","v188","v189","v190","v191",
          "v192","v193","v194","v195","v196","v197","v198","v199",
          "v200","v201","v202","v203","v204","v205","v206","v207",
          "v208","v209","v210","v211","v212","v213","v214","v215",
          "v216","v217","v218","v219","v220","v221","v222","v223",
          "v224","v225","v226","v227","v228","v229","v230","v231",
          "v232","v233","v234","v235","v236","v237",
          "vcc","scc","memory");

    // d >= 0 always so float order == uint order; low 32 bits = idx so
    // equal-d ties pick the smaller index (first-occurrence argmin).
    unsigned long long pk0 =
        ((unsigned long long)__float_as_uint(best0) << 32) | (unsigned)bidx0;
    unsigned long long pk1 =
        ((unsigned long long)__float_as_uint(best1) << 32) | (unsigned)bidx1;
    atomicMin(&packed[t0], pk0);
    atomicMin(&packed[t1], pk1);
}

// ---- unpack chunk-combined argmin, emit idx + counts ----------------------
__global__ __launch_bounds__(256) void kFinish(const unsigned long long* __restrict__ packed,
                                               float* __restrict__ outIdxF,
                                               int* __restrict__ wsIdx,
                                               unsigned* __restrict__ counts) {
    int t = blockIdx.x * 256 + threadIdx.x;
    int idx = (int)(unsigned)(packed[t] & 0xFFFFFFFFull);
    outIdxF[t] = (float)idx;
    wsIdx[t]   = idx;
    atomicAdd(&counts[idx], 1u);
}

// ---- exclusive prefix sum of counts -> bucket offsets ---------------------
__global__ __launch_bounds__(256) void kOffsets(const unsigned* __restrict__ counts,
                                                unsigned* __restrict__ offsets) {
    __shared__ unsigned psum[256];
    int tid = threadIdx.x;
    unsigned local[16];
    unsigned s = 0;
#pragma unroll
    for (int j = 0; j < 16; ++j) { local[j] = s; s += counts[tid * 16 + j]; }
    psum[tid] = s;
    __syncthreads();
    unsigned base = 0;
    for (int i = 0; i < tid; ++i) base += psum[i];
#pragma unroll
    for (int j = 0; j < 16; ++j) offsets[tid * 16 + j] = base + local[j];
}

// ---- scatter token ids into per-code buckets ------------------------------
__global__ __launch_bounds__(256) void kScatter(const int* __restrict__ wsIdx,
                                                const unsigned* __restrict__ offsets,
                                                unsigned* __restrict__ cursor,
                                                int* __restrict__ bucket) {
    int t = blockIdx.x * 256 + threadIdx.x;
    int idx = wsIdx[t];
    unsigned pos = atomicAdd(&cursor[idx], 1u);
    bucket[offsets[idx] + pos] = t;
}

// ---- streaming epilogue: gather, straight-through out, loss partials ------
__global__ __launch_bounds__(256) void kEpilogue(const float* __restrict__ z,
                                                 const float* __restrict__ e,
                                                 const int* __restrict__ wsIdx,
                                                 float* __restrict__ out,
                                                 double* __restrict__ lossPart) {
    __shared__ double lp[4];
    long g = (long)blockIdx.x * 256 + threadIdx.x;   // 0 .. 4194303 (z-linear)
    int b = (int)(g >> 20);
    int r = (int)(g & 1048575);
    int k = r >> 14;
    int s = r & 16383;
    int t = (b << 14) | s;

    float zv = z[g];
    int n = wsIdx[t];
    float eq = e[(n << 6) + k];
    float diff = eq - zv;            // fl(z_q - zp)
    out[g] = zv + diff;              // fl(zp + fl(z_q - zp))  (straight-through)

    double sq = (double)diff * (double)diff;
#pragma unroll
    for (int o = 32; o > 0; o >>= 1) sq += __shfl_down(sq, o);
    if ((threadIdx.x & 63) == 0) lp[threadIdx.x >> 6] = sq;
    __syncthreads();
    if (threadIdx.x == 0) lossPart[blockIdx.x] = (lp[0] + lp[1]) + (lp[2] + lp[3]);
}

// ---- reduce loss partials -------------------------------------------------
__global__ __launch_bounds__(256) void kLoss(const double* __restrict__ lossPart,
                                             double* __restrict__ acc) {
    __shared__ double lp[4];
    double s = 0.0;
    for (int j = 0; j < 64; ++j) s += lossPart[threadIdx.x + j * 256];
#pragma unroll
    for (int o = 32; o > 0; o >>= 1) s += __shfl_down(s, o);
    if ((threadIdx.x & 63) == 0) lp[threadIdx.x >> 6] = s;
    __syncthreads();
    if (threadIdx.x == 0) acc[0] = (lp[0] + lp[1]) + (lp[2] + lp[3]);
}

// ---- EMA part 1: new_cs, n-sum, perplexity partial ------------------------
__global__ __launch_bounds__(256) void kEma1(const float* __restrict__ cs,
                                             const unsigned* __restrict__ counts,
                                             float* __restrict__ outNcs,
                                             double* __restrict__ acc) {
    int n = blockIdx.x * 256 + threadIdx.x;
    float cf = (float)counts[n];
    float p1 = cs[n] * 0.99f;
    float p2 = 0.01f * cf;
    float ncs = p1 + p2;
    outNcs[n] = ncs;
    float p = cf * (1.0f / 65536.0f);          // exact (pow2 divide)
    float term = p * logf(p + 1e-10f);
    double dn = (double)ncs, dt = (double)term;
#pragma unroll
    for (int o = 32; o > 0; o >>= 1) { dn += __shfl_down(dn, o); dt += __shfl_down(dt, o); }
    if ((threadIdx.x & 63) == 0) {
        atomicAdd(&acc[1], dn);
        atomicAdd(&acc[2], dt);
    }
}

// ---- per-code bucket gather: embed_sum -> new_ea, new_embed; scalars ------
__global__ __launch_bounds__(64) void kEsumEma2(const float* __restrict__ z,
                                                const float* __restrict__ ea,
                                                const int* __restrict__ bucket,
                                                const unsigned* __restrict__ offsets,
                                                const unsigned* __restrict__ counts,
                                                const float* __restrict__ ncsArr,
                                                const double* __restrict__ acc,
                                                float* __restrict__ outNemb,
                                                float* __restrict__ outNea,
                                                float* __restrict__ outLoss,
                                                float* __restrict__ outPerp) {
    int n = blockIdx.x;              // code id
    int k = threadIdx.x;             // dim
    unsigned off = offsets[n];
    unsigned cnt = counts[n];
    float es = 0.f;
    for (unsigned i = 0; i < cnt; ++i) {
        int t = bucket[off + i];
        int b = t >> 14;
        int s = t & 16383;
        es += z[(long)b * 1048576 + k * 16384 + s];
    }
    float nea = ea[(n << 6) + k] * 0.99f + 0.01f * es;
    outNea[(n << 6) + k] = nea;
    float nt = (float)acc[1];
    float ncs = ncsArr[n];
    float sc = ((ncs + 1e-5f) / (nt + 0.04096f)) * nt;
    outNemb[(n << 6) + k] = nea / sc;
    if (n == 0 && k == 0) {
        double m = acc[0] / 4194304.0;
        outLoss[0] = 0.25f * (float)m;
        outPerp[0] = (float)exp(-acc[2]);
    }
}

extern "C" void kernel_launch(void* const* d_in, const int* in_sizes, int n_in,
                              void* d_out, int out_size, void* d_ws, size_t ws_size,
                              hipStream_t stream) {
    const float* z  = (const float*)d_in[0];
    const float* ew = (const float*)d_in[1];
    const float* cs = (const float*)d_in[2];
    const float* ea = (const float*)d_in[3];
    float* out = (float*)d_out;
    char* ws = (char*)d_ws;

    double*   acc    = (double*)(ws + W_ACC);
    unsigned* counts = (unsigned*)(ws + W_CNT);
    unsigned* cursor = (unsigned*)(ws + W_CUR);
    unsigned* offs   = (unsigned*)(ws + W_OFF);
    int*      wsIdx  = (int*)(ws + W_IDX);
    int*      bucket = (int*)(ws + W_BKT);
    double*   lossP  = (double*)(ws + W_LOSSP);
    unsigned long long* packed = (unsigned long long*)(ws + W_PKD);
    float*    aug    = (float*)(ws + W_AUG);

    hipMemsetAsync(ws, 0, W_ZERO_BYTES, stream);
    hipMemsetAsync(ws + W_PKD, 0xFF, W_PKD_BYTES, stream);
    kAug<<<NE / 256, 256, 0, stream>>>(ew, aug);
    kArgmin<<<(NTOK / 512) * NCHUNK, 256, 0, stream>>>(z, aug, packed);
    kFinish<<<NTOK / 256, 256, 0, stream>>>(packed, out + O_IDX, wsIdx, counts);
    kOffsets<<<1, 256, 0, stream>>>(counts, offs);
    kScatter<<<NTOK / 256, 256, 0, stream>>>(wsIdx, offs, cursor, bucket);
    kEpilogue<<<16384, 256, 0, stream>>>(z, ew, wsIdx, out + O_OUT, lossP);
    kLoss<<<1, 256, 0, stream>>>(lossP, acc);
    kEma1<<<NE / 256, 256, 0, stream>>>(cs, counts, out + O_NCS, acc);
    kEsumEma2<<<NE, 64, 0, stream>>>(z, ea, bucket, offs, counts, out + O_NCS, acc,
                                     out + O_NEMB, out + O_NEA,
                                     out + O_LOSS, out + O_PERP);
}

// Round 13
// 575.544 us; speedup vs baseline: 1.1640x; 1.0010x over previous
//
#include <hip/hip_runtime.h>

static constexpr int NE   = 4096;      // n_embed
static constexpr int ED   = 64;        // embed_dim
static constexpr int NTOK = 65536;     // 4*16*32*32
static constexpr int NCHUNK = 32;      // code-loop split factor
static constexpr int CPC  = NE / NCHUNK;   // codes per chunk = 128

typedef float  f32x2 __attribute__((ext_vector_type(2)));
typedef float  f32x4 __attribute__((ext_vector_type(4)));

// d_out offsets (float elements), outputs concatenated in return order:
// out(4194304), loss(1), perplexity(1), idx(65536), new_embed(262144),
// new_cs(4096), new_ea(262144)
static constexpr long O_OUT  = 0;
static constexpr long O_LOSS = 4194304;
static constexpr long O_PERP = 4194305;
static constexpr long O_IDX  = 4194306;
static constexpr long O_NEMB = 4259842;
static constexpr long O_NCS  = 4521986;
static constexpr long O_NEA  = 4526082;

// ws layout (bytes)
static constexpr size_t W_ACC   = 0;        // double[4]: [0]=loss [1]=n [2]=plog   (zeroed)
static constexpr size_t W_CNT   = 32;       // unsigned[4096] counts                (zeroed)
static constexpr size_t W_CUR   = 16416;    // unsigned[4096] scatter cursors       (zeroed)
static constexpr size_t W_OFF   = 32800;    // unsigned[4096] bucket start offsets
static constexpr size_t W_IDX   = 49184;    // int[65536]
static constexpr size_t W_BKT   = 311328;   // int[65536] token ids bucketed by code
static constexpr size_t W_LOSSP = 573472;   // double[16384] per-block loss partials
static constexpr size_t W_PKD   = 704544;   // uint64[65536] packed (d_bits<<32)|idx
static constexpr size_t W_AUG   = 1228832;  // float[4096*68]: [e row (64), bq, pad(3)]
static constexpr size_t W_ZERO_BYTES = 32800;   // acc + counts + cursors
static constexpr size_t W_PKD_BYTES  = 524288;  // 0xFF-init packed

// ---- augmented codebook: row n = [e_n[0..63], ||e_n||^2, pad] (stride 68) --
__global__ __launch_bounds__(256) void kAug(const float* __restrict__ e,
                                            float* __restrict__ aug) {
    int n = blockIdx.x * 256 + threadIdx.x;        // 0..4095
    const float* er = e + (n << 6);
    float* row = aug + (long)n * 68;
    // bq numerics: identical fmaf 4-partial chain to the 12x-passing kBsq
    float a0 = 0.f, a1 = 0.f, a2 = 0.f, a3 = 0.f;
#pragma unroll
    for (int k = 0; k < ED; k += 4) {
        a0 = fmaf(er[k+0], er[k+0], a0);
        a1 = fmaf(er[k+1], er[k+1], a1);
        a2 = fmaf(er[k+2], er[k+2], a2);
        a3 = fmaf(er[k+3], er[k+3], a3);
    }
#pragma unroll
    for (int k = 0; k < 16; ++k)
        ((f32x4*)row)[k] = ((const f32x4*)er)[k];
    row[64] = (a0 + a1) + (a2 + a3);
}

// ---- asm text helper macros ------------------------------------------------
#define ZLD(VD) \
    "global_load_dword v" #VD ", v251, %[zb]\n\t" \
    "v_add_u32 v251, 0x10000, v251\n\t"
#define AMUL(C, Z) "v_mul_f32 v" #C ", v" #Z ", v" #Z "\n\t"
#define AFMA(C, Z) "v_fma_f32 v" #C ", v" #Z ", v" #Z ", v" #C "\n\t"
#define AQ4(Z0,Z1,Z2,Z3) AFMA(241,Z0) AFMA(242,Z1) AFMA(243,Z2) AFMA(244,Z3)
#define BQ4(Z0,Z1,Z2,Z3) AFMA(245,Z0) AFMA(246,Z1) AFMA(247,Z2) AFMA(248,Z3)
#define M2(CA,CB,ZA,ZB,E) \
    "v_mul_f32 v" #CA ", v" #ZA ", v" #E "\n\t" \
    "v_mul_f32 v" #CB ", v" #ZB ", v" #E "\n\t"
#define D2(CA,CB,ZA,ZB,E) \
    "v_fma_f32 v" #CA ", v" #ZA ", v" #E ", v" #CA "\n\t" \
    "v_fma_f32 v" #CB ", v" #ZB ", v" #E ", v" #CB "\n\t"

// quarter read groups (banks fixed per quarter; bq rides with Q3)
#define RD_Q0 \
    "ds_read_b128 v[176:179], %[va] offset:0\n\t" \
    "ds_read_b128 v[180:183], %[va] offset:16\n\t" \
    "ds_read_b128 v[184:187], %[va] offset:32\n\t" \
    "ds_read_b128 v[188:191], %[va] offset:48\n\t"
#define RD_Q1 \
    "ds_read_b128 v[192:195], %[va] offset:64\n\t" \
    "ds_read_b128 v[196:199], %[va] offset:80\n\t" \
    "ds_read_b128 v[200:203], %[va] offset:96\n\t" \
    "ds_read_b128 v[204:207], %[va] offset:112\n\t"
#define RD_Q2 \
    "ds_read_b128 v[208:211], %[va] offset:128\n\t" \
    "ds_read_b128 v[212:215], %[va] offset:144\n\t" \
    "ds_read_b128 v[216:219], %[va] offset:160\n\t" \
    "ds_read_b128 v[220:223], %[va] offset:176\n\t"
#define RD_Q3 \
    "ds_read_b128 v[224:227], %[va] offset:192\n\t" \
    "ds_read_b128 v[228:231], %[va] offset:208\n\t" \
    "ds_read_b128 v[232:235], %[va] offset:224\n\t" \
    "ds_read_b128 v[236:239], %[va] offset:240\n\t" \
    "ds_read_b32 v240, %[va] offset:256\n\t"

// ---- argmin over a 128-code chunk, TWO tokens per thread -------------------
// grid = 4096 blocks: block = (tokenBlock<<5) | chunk; tokens t0 = tb*512+tid,
// t1 = t0+256 (same batch: 16384 % 512 == 0).
// r12 post-mortem: wall = VALU(580cyc) + DS(544cyc) ADDITIVE per round — the
// 1-quarter-ahead pipeline left only ~64cyc cover vs ~120cyc LDS latency +
// queueing, so every lgkmcnt wait stalled and 2 waves/SIMD couldn't fill it.
// Fix: 4 fixed banks (Q0-Q3), issue 3 quarters AHEAD (~200cyc cover), counted
// lgkmcnt(13/12) waits (DS completes in-order per wave -> counted waits are
// exact). Rotation period = 1 row -> loop body unchanged. FMA chains are the
// same ascending-dim 4-partial recurrence -> bit-identical distances.
// Regs: v48-111 z-t0, v112-175 z-t1, banks v176/192/208/224(+16), v240 bq,
// v241-244 chains t0, v245-248 chains t1, v249 A0, v250 A1, v251/252 tmp,
// v253 idx counter.
__global__ __launch_bounds__(256, 2) void kArgmin(const float* __restrict__ z,
                                                  const float* __restrict__ aug,
                                                  unsigned long long* __restrict__ packed) {
    __shared__ alignas(16) float lds[CPC * 68 + 48];   // 35,008 B (192B prefetch pad)
    int bid = blockIdx.x;
    int tb = bid >> 5;
    int chunk = bid & 31;

    // stage this chunk's aug rows into LDS (34,816B contiguous, f32x2 copy)
    {
        const f32x2* src = (const f32x2*)(aug + (long)(chunk * CPC) * 68);
        f32x2* dst = (f32x2*)lds;
#pragma unroll
        for (int i = 0; i < 17; ++i)
            dst[threadIdx.x + i * 256] = src[threadIdx.x + i * 256];
    }
    __syncthreads();

    int t0 = tb * 512 + threadIdx.x;            // token 0
    int t1 = t0 + 256;                          // token 1 (same batch)
    int b  = t0 >> 14;
    int s0 = t0 & 16383;
    unsigned off0 = ((unsigned)b * 1048576u + (unsigned)s0) * 4u;  // byte offset
    unsigned off1 = off0 + 1024u;               // +256 tokens * 4B

    int c0i = chunk * CPC;
    float best0 = __builtin_inff(), best1 = __builtin_inff();
    int bidx0 = c0i, bidx1 = c0i;
    unsigned va0 = (unsigned)(unsigned long long)(&lds[0]);

    asm volatile(
        // ---- prologue: load z for both tokens (dim stride 0x10000 B) ----
        "v_mov_b32 v251, %[off0]\n\t"
        ZLD(48)  ZLD(49)  ZLD(50)  ZLD(51)  ZLD(52)  ZLD(53)  ZLD(54)  ZLD(55)
        ZLD(56)  ZLD(57)  ZLD(58)  ZLD(59)  ZLD(60)  ZLD(61)  ZLD(62)  ZLD(63)
        ZLD(64)  ZLD(65)  ZLD(66)  ZLD(67)  ZLD(68)  ZLD(69)  ZLD(70)  ZLD(71)
        ZLD(72)  ZLD(73)  ZLD(74)  ZLD(75)  ZLD(76)  ZLD(77)  ZLD(78)  ZLD(79)
        ZLD(80)  ZLD(81)  ZLD(82)  ZLD(83)  ZLD(84)  ZLD(85)  ZLD(86)  ZLD(87)
        ZLD(88)  ZLD(89)  ZLD(90)  ZLD(91)  ZLD(92)  ZLD(93)  ZLD(94)  ZLD(95)
        ZLD(96)  ZLD(97)  ZLD(98)  ZLD(99)  ZLD(100) ZLD(101) ZLD(102) ZLD(103)
        ZLD(104) ZLD(105) ZLD(106) ZLD(107) ZLD(108) ZLD(109) ZLD(110) ZLD(111)
        "v_mov_b32 v251, %[off1]\n\t"
        ZLD(112) ZLD(113) ZLD(114) ZLD(115) ZLD(116) ZLD(117) ZLD(118) ZLD(119)
        ZLD(120) ZLD(121) ZLD(122) ZLD(123) ZLD(124) ZLD(125) ZLD(126) ZLD(127)
        ZLD(128) ZLD(129) ZLD(130) ZLD(131) ZLD(132) ZLD(133) ZLD(134) ZLD(135)
        ZLD(136) ZLD(137) ZLD(138) ZLD(139) ZLD(140) ZLD(141) ZLD(142) ZLD(143)
        ZLD(144) ZLD(145) ZLD(146) ZLD(147) ZLD(148) ZLD(149) ZLD(150) ZLD(151)
        ZLD(152) ZLD(153) ZLD(154) ZLD(155) ZLD(156) ZLD(157) ZLD(158) ZLD(159)
        ZLD(160) ZLD(161) ZLD(162) ZLD(163) ZLD(164) ZLD(165) ZLD(166) ZLD(167)
        ZLD(168) ZLD(169) ZLD(170) ZLD(171) ZLD(172) ZLD(173) ZLD(174) ZLD(175)
        "s_waitcnt vmcnt(0)\n\t"
        // ---- A0 = sum z0^2 (reference 4-partial chain, ascending) ----
        AMUL(241,48) AMUL(242,49) AMUL(243,50) AMUL(244,51)
        AQ4(52,53,54,55)     AQ4(56,57,58,59)     AQ4(60,61,62,63)
        AQ4(64,65,66,67)     AQ4(68,69,70,71)     AQ4(72,73,74,75)
        AQ4(76,77,78,79)     AQ4(80,81,82,83)     AQ4(84,85,86,87)
        AQ4(88,89,90,91)     AQ4(92,93,94,95)     AQ4(96,97,98,99)
        AQ4(100,101,102,103) AQ4(104,105,106,107) AQ4(108,109,110,111)
        "v_add_f32 v249, v241, v242\n\t"
        "v_add_f32 v251, v243, v244\n\t"
        "v_add_f32 v249, v249, v251\n\t"          // A0
        // ---- A1 = sum z1^2 ----
        AMUL(245,112) AMUL(246,113) AMUL(247,114) AMUL(248,115)
        BQ4(116,117,118,119) BQ4(120,121,122,123) BQ4(124,125,126,127)
        BQ4(128,129,130,131) BQ4(132,133,134,135) BQ4(136,137,138,139)
        BQ4(140,141,142,143) BQ4(144,145,146,147) BQ4(148,149,150,151)
        BQ4(152,153,154,155) BQ4(156,157,158,159) BQ4(160,161,162,163)
        BQ4(164,165,166,167) BQ4(168,169,170,171) BQ4(172,173,174,175)
        "v_add_f32 v250, v245, v246\n\t"
        "v_add_f32 v251, v247, v248\n\t"
        "v_add_f32 v250, v250, v251\n\t"          // A1
        // ---- loop setup + 3-quarter preload (q0,q1,q2 of row 0) ----
        "s_mov_b32 s32, 0\n\t"
        "v_mov_b32 v253, %[n0]\n\t"
        RD_Q0
        RD_Q1
        RD_Q2
        "1:\n\t"
        // step q0: issue q3(r)+bq; wait q0(r) [3 steps ago]; compute q0
        RD_Q3
        "s_waitcnt lgkmcnt(13)\n\t"
        M2(241,245,48,112,176) M2(242,246,49,113,177)
        M2(243,247,50,114,178) M2(244,248,51,115,179)
        D2(241,245,52,116,180) D2(242,246,53,117,181)
        D2(243,247,54,118,182) D2(244,248,55,119,183)
        D2(241,245,56,120,184) D2(242,246,57,121,185)
        D2(243,247,58,122,186) D2(244,248,59,123,187)
        D2(241,245,60,124,188) D2(242,246,61,125,189)
        D2(243,247,62,126,190) D2(244,248,63,127,191)
        // step q1: bump row ptr; issue q0(r+1); wait q1(r); compute q1
        "v_add_u32 %[va], 0x110, %[va]\n\t"
        RD_Q0
        "s_waitcnt lgkmcnt(13)\n\t"
        D2(241,245,64,128,192) D2(242,246,65,129,193)
        D2(243,247,66,130,194) D2(244,248,67,131,195)
        D2(241,245,68,132,196) D2(242,246,69,133,197)
        D2(243,247,70,134,198) D2(244,248,71,135,199)
        D2(241,245,72,136,200) D2(242,246,73,137,201)
        D2(243,247,74,138,202) D2(244,248,75,139,203)
        D2(241,245,76,140,204) D2(242,246,77,141,205)
        D2(243,247,78,142,206) D2(244,248,79,143,207)
        // step q2: issue q1(r+1); wait q2(r); compute q2
        RD_Q1
        "s_waitcnt lgkmcnt(13)\n\t"
        D2(241,245,80,144,208) D2(242,246,81,145,209)
        D2(243,247,82,146,210) D2(244,248,83,147,211)
        D2(241,245,84,148,212) D2(242,246,85,149,213)
        D2(243,247,86,150,214) D2(244,248,87,151,215)
        D2(241,245,88,152,216) D2(242,246,89,153,217)
        D2(243,247,90,154,218) D2(244,248,91,155,219)
        D2(241,245,92,156,220) D2(242,246,93,157,221)
        D2(243,247,94,158,222) D2(244,248,95,159,223)
        // step q3: issue q2(r+1); wait q3(r)+bq; compute q3 + tails
        RD_Q2
        "s_waitcnt lgkmcnt(12)\n\t"
        D2(241,245,96,160,224)  D2(242,246,97,161,225)
        D2(243,247,98,162,226)  D2(244,248,99,163,227)
        D2(241,245,100,164,228) D2(242,246,101,165,229)
        D2(243,247,102,166,230) D2(244,248,103,167,231)
        D2(241,245,104,168,232) D2(242,246,105,169,233)
        D2(243,247,106,170,234) D2(244,248,107,171,235)
        D2(241,245,108,172,236) D2(242,246,109,173,237)
        D2(243,247,110,174,238) D2(244,248,111,175,239)
        // tails: d = fl((A+bq) - 2*dot), strict-< min track (t0 then t1)
        "v_add_f32 v251, v241, v242\n\t"
        "v_add_f32 v252, v243, v244\n\t"
        "v_add_f32 v251, v251, v252\n\t"
        "v_add_f32 v252, v240, v249\n\t"
        "v_fma_f32 v251, -2.0, v251, v252\n\t"
        "v_cmp_lt_f32 vcc, v251, %[best0]\n\t"
        "v_cndmask_b32 %[best0], %[best0], v251, vcc\n\t"
        "v_cndmask_b32 %[bidx0], %[bidx0], v253, vcc\n\t"
        "v_add_f32 v251, v245, v246\n\t"
        "v_add_f32 v252, v247, v248\n\t"
        "v_add_f32 v251, v251, v252\n\t"
        "v_add_f32 v252, v240, v250\n\t"
        "v_fma_f32 v251, -2.0, v251, v252\n\t"
        "v_cmp_lt_f32 vcc, v251, %[best1]\n\t"
        "v_cndmask_b32 %[best1], %[best1], v251, vcc\n\t"
        "v_cndmask_b32 %[bidx1], %[bidx1], v253, vcc\n\t"
        "v_add_u32 v253, 1, v253\n\t"
        "s_add_u32 s32, s32, 1\n\t"
        "s_cmp_lt_u32 s32, 0x80\n\t"
        "s_cbranch_scc1 1b\n\t"
        "s_waitcnt lgkmcnt(0)\n\t"                 // drain dangling prefetches
        : [best0]"+v"(best0), [bidx0]"+v"(bidx0),
          [best1]"+v"(best1), [bidx1]"+v"(bidx1), [va]"+v"(va0)
        : [zb]"s"(z), [off0]"v"(off0), [off1]"v"(off1), [n0]"v"(c0i)
        : "s32", "vcc", "scc", "memory",
          "v48","v49","v50","v51","v52","v53","v54","v55",
          "v56","v57","v58","v59","v60","v61","v62","v63",
          "v64","v65","v66","v67","v68","v69","v70","v71",
          "v72","v73","v74","v75","v76","v77","v78","v79",
          "v80","v81","v82","v83","v84","v85","v86","v87",
          "v88","v89","v90","v91","v92","v93","v94","v95",
          "v96","v97","v98","v99","v100","v101","v102","v103",
          "v104","v105","v106","v107","v108","v109","v110","v111",
          "v112","v113","v114","v115","v116","v117","v118","v119",
          "v120","v121","v122","v123","v124","v125","v126","v127",
          "v128","v129","v130","v131","v132","v133","v134","v135",
          "v136","v137","v138","v139","v140","v141","v142","v143",
          "v144","v145","v146","v147","v148","v149","v150","v151",
          "v152","v153","v154","v155","v156","v157","v158","v159",
          "v160","v161","v162","v163","v164","v165","v166","v167",
          "v168","v169","v170","v171","v172","v173","v174","v175",
          "v176","v177","v178","v179","v180","v181","v182","v183",
          "v184","v185","v186","v187","v188","v189","v190","v191",
          "v192","v193","v194","v195","v196","v197","v198","v199",
          "v200","v201","v202","v203","v204","v205","v206","v207",
          "v208","v209","v210","v211","v212","v213","v214","v215",
          "v216","v217","v218","v219","v220","v221","v222","v223",
          "v224","v225","v226","v227","v228","v229","v230","v231",
          "v232","v233","v234","v235","v236","v237","v238","v239",
          "v240","v241","v242","v243","v244","v245","v246","v247",
          "v248","v249","v250","v251","v252","v253");

    // d >= 0 always so float order == uint order; low 32 bits = idx so
    // equal-d ties pick the smaller index (first-occurrence argmin).
    unsigned long long pk0 =
        ((unsigned long long)__float_as_uint(best0) << 32) | (unsigned)bidx0;
    unsigned long long pk1 =
        ((unsigned long long)__float_as_uint(best1) << 32) | (unsigned)bidx1;
    atomicMin(&packed[t0], pk0);
    atomicMin(&packed[t1], pk1);
}

// ---- unpack chunk-combined argmin, emit idx + counts ----------------------
__global__ __launch_bounds__(256) void kFinish(const unsigned long long* __restrict__ packed,
                                               float* __restrict__ outIdxF,
                                               int* __restrict__ wsIdx,
                                               unsigned* __restrict__ counts) {
    int t = blockIdx.x * 256 + threadIdx.x;
    int idx = (int)(unsigned)(packed[t] & 0xFFFFFFFFull);
    outIdxF[t] = (float)idx;
    wsIdx[t]   = idx;
    atomicAdd(&counts[idx], 1u);
}

// ---- exclusive prefix sum of counts -> bucket offsets ---------------------
__global__ __launch_bounds__(256) void kOffsets(const unsigned* __restrict__ counts,
                                                unsigned* __restrict__ offsets) {
    __shared__ unsigned psum[256];
    int tid = threadIdx.x;
    unsigned local[16];
    unsigned s = 0;
#pragma unroll
    for (int j = 0; j < 16; ++j) { local[j] = s; s += counts[tid * 16 + j]; }
    psum[tid] = s;
    __syncthreads();
    unsigned base = 0;
    for (int i = 0; i < tid; ++i) base += psum[i];
#pragma unroll
    for (int j = 0; j < 16; ++j) offsets[tid * 16 + j] = base + local[j];
}

// ---- scatter token ids into per-code buckets ------------------------------
__global__ __launch_bounds__(256) void kScatter(const int* __restrict__ wsIdx,
                                                const unsigned* __restrict__ offsets,
                                                unsigned* __restrict__ cursor,
                                                int* __restrict__ bucket) {
    int t = blockIdx.x * 256 + threadIdx.x;
    int idx = wsIdx[t];
    unsigned pos = atomicAdd(&cursor[idx], 1u);
    bucket[offsets[idx] + pos] = t;
}

// ---- streaming epilogue: gather, straight-through out, loss partials ------
__global__ __launch_bounds__(256) void kEpilogue(const float* __restrict__ z,
                                                 const float* __restrict__ e,
                                                 const int* __restrict__ wsIdx,
                                                 float* __restrict__ out,
                                                 double* __restrict__ lossPart) {
    __shared__ double lp[4];
    long g = (long)blockIdx.x * 256 + threadIdx.x;   // 0 .. 4194303 (z-linear)
    int b = (int)(g >> 20);
    int r = (int)(g & 1048575);
    int k = r >> 14;
    int s = r & 16383;
    int t = (b << 14) | s;

    float zv = z[g];
    int n = wsIdx[t];
    float eq = e[(n << 6) + k];
    float diff = eq - zv;            // fl(z_q - zp)
    out[g] = zv + diff;              // fl(zp + fl(z_q - zp))  (straight-through)

    double sq = (double)diff * (double)diff;
#pragma unroll
    for (int o = 32; o > 0; o >>= 1) sq += __shfl_down(sq, o);
    if ((threadIdx.x & 63) == 0) lp[threadIdx.x >> 6] = sq;
    __syncthreads();
    if (threadIdx.x == 0) lossPart[blockIdx.x] = (lp[0] + lp[1]) + (lp[2] + lp[3]);
}

// ---- reduce loss partials -------------------------------------------------
__global__ __launch_bounds__(256) void kLoss(const double* __restrict__ lossPart,
                                             double* __restrict__ acc) {
    __shared__ double lp[4];
    double s = 0.0;
    for (int j = 0; j < 64; ++j) s += lossPart[threadIdx.x + j * 256];
#pragma unroll
    for (int o = 32; o > 0; o >>= 1) s += __shfl_down(s, o);
    if ((threadIdx.x & 63) == 0) lp[threadIdx.x >> 6] = s;
    __syncthreads();
    if (threadIdx.x == 0) acc[0] = (lp[0] + lp[1]) + (lp[2] + lp[3]);
}

// ---- EMA part 1: new_cs, n-sum, perplexity partial ------------------------
__global__ __launch_bounds__(256) void kEma1(const float* __restrict__ cs,
                                             const unsigned* __restrict__ counts,
                                             float* __restrict__ outNcs,
                                             double* __restrict__ acc) {
    int n = blockIdx.x * 256 + threadIdx.x;
    float cf = (float)counts[n];
    float p1 = cs[n] * 0.99f;
    float p2 = 0.01f * cf;
    float ncs = p1 + p2;
    outNcs[n] = ncs;
    float p = cf * (1.0f / 65536.0f);          // exact (pow2 divide)
    float term = p * logf(p + 1e-10f);
    double dn = (double)ncs, dt = (double)term;
#pragma unroll
    for (int o = 32; o > 0; o >>= 1) { dn += __shfl_down(dn, o); dt += __shfl_down(dt, o); }
    if ((threadIdx.x & 63) == 0) {
        atomicAdd(&acc[1], dn);
        atomicAdd(&acc[2], dt);
    }
}

// ---- per-code bucket gather: embed_sum -> new_ea, new_embed; scalars ------
__global__ __launch_bounds__(64) void kEsumEma2(const float* __restrict__ z,
                                                const float* __restrict__ ea,
                                                const int* __restrict__ bucket,
                                                const unsigned* __restrict__ offsets,
                                                const unsigned* __restrict__ counts,
                                                const float* __restrict__ ncsArr,
                                                const double* __restrict__ acc,
                                                float* __restrict__ outNemb,
                                                float* __restrict__ outNea,
                                                float* __restrict__ outLoss,
                                                float* __restrict__ outPerp) {
    int n = blockIdx.x;              // code id
    int k = threadIdx.x;             // dim
    unsigned off = offsets[n];
    unsigned cnt = counts[n];
    float es = 0.f;
    for (unsigned i = 0; i < cnt; ++i) {
        int t = bucket[off + i];
        int b = t >> 14;
        int s = t & 16383;
        es += z[(long)b * 1048576 + k * 16384 + s];
    }
    float nea = ea[(n << 6) + k] * 0.99f + 0.01f * es;
    outNea[(n << 6) + k] = nea;
    float nt = (float)acc[1];
    float ncs = ncsArr[n];
    float sc = ((ncs + 1e-5f) / (nt + 0.04096f)) * nt;
    outNemb[(n << 6) + k] = nea / sc;
    if (n == 0 && k == 0) {
        double m = acc[0] / 4194304.0;
        outLoss[0] = 0.25f * (float)m;
        outPerp[0] = (float)exp(-acc[2]);
    }
}

extern "C" void kernel_launch(void* const* d_in, const int* in_sizes, int n_in,
                              void* d_out, int out_size, void* d_ws, size_t ws_size,
                              hipStream_t stream) {
    const float* z  = (const float*)d_in[0];
    const float* ew = (const float*)d_in[1];
    const float* cs = (const float*)d_in[2];
    const float* ea = (const float*)d_in[3];
    float* out = (float*)d_out;
    char* ws = (char*)d_ws;

    double*   acc    = (double*)(ws + W_ACC);
    unsigned* counts = (unsigned*)(ws + W_CNT);
    unsigned* cursor = (unsigned*)(ws + W_CUR);
    unsigned* offs   = (unsigned*)(ws + W_OFF);
    int*      wsIdx  = (int*)(ws + W_IDX);
    int*      bucket = (int*)(ws + W_BKT);
    double*   lossP  = (double*)(ws + W_LOSSP);
    unsigned long long* packed = (unsigned long long*)(ws + W_PKD);
    float*    aug    = (float*)(ws + W_AUG);

    hipMemsetAsync(ws, 0, W_ZERO_BYTES, stream);
    hipMemsetAsync(ws + W_PKD, 0xFF, W_PKD_BYTES, stream);
    kAug<<<NE / 256, 256, 0, stream>>>(ew, aug);
    kArgmin<<<(NTOK / 512) * NCHUNK, 256, 0, stream>>>(z, aug, packed);
    kFinish<<<NTOK / 256, 256, 0, stream>>>(packed, out + O_IDX, wsIdx, counts);
    kOffsets<<<1, 256, 0, stream>>>(counts, offs);
    kScatter<<<NTOK / 256, 256, 0, stream>>>(wsIdx, offs, cursor, bucket);
    kEpilogue<<<16384, 256, 0, stream>>>(z, ew, wsIdx, out + O_OUT, lossP);
    kLoss<<<1, 256, 0, stream>>>(lossP, acc);
    kEma1<<<NE / 256, 256, 0, stream>>>(cs, counts, out + O_NCS, acc);
    kEsumEma2<<<NE, 64, 0, stream>>>(z, ea, bucket, offs, counts, out + O_NCS, acc,
                                     out + O_NEMB, out + O_NEA,
                                     out + O_LOSS, out + O_PERP);
}